// Round 16
// baseline (42.279 us; speedup 1.0000x reference)
//
#include <hip/hip_runtime.h>
#include <hip/hip_bf16.h>

// out[d,t] = (sum_j exp(s[t,j]) * u[j,d]) / (sum_j exp(s[t,j]))
// Fused exp-GEMM.
// R16: K-SPLIT B staging — R8's proven geometry (512 blocks x 512 threads,
// one 16-row tile per wave, 128 rows/block, depth-4 register prefetch) but B
// lives in a 64KB LDS buffer holding HALF the K range, refilled once at g=8
// (barrier -> fill -> barrier). The s-walk is the identical linear 16-step
// stream (k-offset = g*32); per-element arithmetic and accumulation order are
// bit-identical to R4/R8 (absmax must be exactly 0.00390625). Zero duplicated
// work. Payoff: 64KB LDS -> 2 blocks/CU co-resident -> 4 waves/SIMD (TLP 2x),
// the lever every prior attempt bought with duplication (R13) or
// allocator-hostile shapes (R5/R7/R11/R14: 1024-thr/2-tile always spill).
// Body stays in the (512,2) no-spill class: ~110 VGPR est.

constexpr int T_DIM = 65536;
constexpr int J_DIM = 512;
constexpr int D_DIM = 128;
constexpr int KK_PER_PASS = 8;         // K-chunks resident in LDS at once
constexpr int NSTEP = 16;              // total K-chunks (512 / 32)
constexpr int NFRAG = 8;               // 8 N-fragments covering D=128
constexpr int PF_DEPTH = 4;            // s-load prefetch depth (iterations)
constexpr int BP_ELEMS = KK_PER_PASS * NFRAG * 64;   // 4096 s16x8 = 64KB

typedef __attribute__((ext_vector_type(4))) float  f32x4;
typedef __attribute__((ext_vector_type(8))) short  s16x8;
typedef __attribute__((ext_vector_type(8))) __bf16 bf16x8;

__device__ __forceinline__ short f2bf_rne(float f) {
    unsigned u = __builtin_bit_cast(unsigned, f);
    u += 0x7fffu + ((u >> 16) & 1u);   // round-to-nearest-even
    return (short)(u >> 16);
}

__device__ __forceinline__ void fill_b(int pass, const float* __restrict__ u,
                                       s16x8* __restrict__ bsh, int tid) {
    // element e: lane=e&63, nf=(e>>6)&7, kk=e>>9 (0..7);
    //   d = nf*16 + (e&15), k0 = pass*256 + kk*32 + 8*((e>>4)&3)
#pragma unroll 4
    for (int it = 0; it < BP_ELEMS / 512; ++it) {
        int e  = it * 512 + tid;
        int d  = ((e >> 6) & (NFRAG - 1)) * 16 + (e & 15);
        int k0 = pass * 256 + (e >> 9) * 32 + 8 * ((e >> 4) & 3);
        const float* up = u + (size_t)k0 * D_DIM + d;
        s16x8 o;
#pragma unroll
        for (int i = 0; i < 8; ++i)
            o[i] = f2bf_rne(up[(size_t)i * D_DIM]);
        bsh[e] = o;
    }
}

__global__ __launch_bounds__(512, 2) void c2q_main(const float* __restrict__ sm,
                                                   const float* __restrict__ u,
                                                   float* __restrict__ out) {
    __shared__ s16x8 bsh[BP_ELEMS];    // [kk(8)][nf(8)][lane] — 65536 bytes

    const int tid  = threadIdx.x;
    const int l    = tid & 63;
    const int w    = tid >> 6;        // wave 0..7
    const int lmod = l & 15;
    const int lh   = l >> 4;          // 0..3
    const int r0   = blockIdx.x * 128 + w * 16;  // this wave's first t-row

    // A-fragment source: lane holds row r0+lmod, k = g*32 + 8*lh + i
    // -> one linear 16-step walk of 32B chunks, identical to R8.
    const float* sp = sm + (size_t)(r0 + lmod) * J_DIM + lh * 8;

    // ---- prologue: prefetch iterations 0..3 ----
    f32x4 sbuf[PF_DEPTH][2];
#pragma unroll
    for (int p = 0; p < PF_DEPTH; ++p) {
        sbuf[p][0] = *reinterpret_cast<const f32x4*>(sp + p * 32);
        sbuf[p][1] = *reinterpret_cast<const f32x4*>(sp + p * 32 + 4);
    }

    // ---- B fill, K-half 0 (u is L2/L3-resident) ----
    fill_b(0, u, bsh, tid);
    __syncthreads();

    f32x4 acc[NFRAG];
#pragma unroll
    for (int nf = 0; nf < NFRAG; ++nf) acc[nf] = (f32x4){0.f, 0.f, 0.f, 0.f};
    float den = 0.f;

#pragma unroll
    for (int g = 0; g < NSTEP; ++g) {
        if (g == KK_PER_PASS) {
            __syncthreads();           // all waves done reading K-half 0
            fill_b(1, u, bsh, tid);
            __syncthreads();           // K-half 1 visible
        }
        const int slot = g & (PF_DEPTH - 1);     // compile-time after unroll
        f32x4 s0 = sbuf[slot][0];
        f32x4 s1 = sbuf[slot][1];
        if (g + PF_DEPTH < NSTEP) {              // refill for iteration g+4
            sbuf[slot][0] =
                *reinterpret_cast<const f32x4*>(sp + (g + PF_DEPTH) * 32);
            sbuf[slot][1] =
                *reinterpret_cast<const f32x4*>(sp + (g + PF_DEPTH) * 32 + 4);
        }
        float e0 = __expf(s0[0]), e1 = __expf(s0[1]);
        float e2 = __expf(s0[2]), e3 = __expf(s0[3]);
        float e4 = __expf(s1[0]), e5 = __expf(s1[1]);
        float e6 = __expf(s1[2]), e7 = __expf(s1[3]);
        den += ((e0 + e1) + (e2 + e3)) + ((e4 + e5) + (e6 + e7));
        s16x8 a;
        a[0] = f2bf_rne(e0); a[1] = f2bf_rne(e1);
        a[2] = f2bf_rne(e2); a[3] = f2bf_rne(e3);
        a[4] = f2bf_rne(e4); a[5] = f2bf_rne(e5);
        a[6] = f2bf_rne(e6); a[7] = f2bf_rne(e7);
        bf16x8 av = __builtin_bit_cast(bf16x8, a);
        const int kk = g & (KK_PER_PASS - 1);    // slot within resident half
#pragma unroll
        for (int nf = 0; nf < NFRAG; ++nf) {
            bf16x8 bv = __builtin_bit_cast(bf16x8, bsh[(kk * NFRAG + nf) * 64 + l]);
            acc[nf] = __builtin_amdgcn_mfma_f32_16x16x32_bf16(av, bv, acc[nf], 0, 0, 0);
        }
        __builtin_amdgcn_sched_barrier(0);       // keep per-iteration structure
    }

    // den(l) holds row lmod's partial over k-chunk lh: reduce the 4 chunks.
    den += __shfl_xor(den, 16, 64);
    den += __shfl_xor(den, 32, 64);
    // C/D layout: col = lane&15 (-> d), row = 4*(lane>>4)+reg (-> t).
    float inv[4];
#pragma unroll
    for (int r = 0; r < 4; ++r)
        inv[r] = 1.0f / __shfl(den, 4 * lh + r, 64);

#pragma unroll
    for (int nf = 0; nf < NFRAG; ++nf) {
        f32x4 v;
#pragma unroll
        for (int r = 0; r < 4; ++r) v[r] = acc[nf][r] * inv[r];
        *reinterpret_cast<f32x4*>(out + (size_t)(nf * 16 + lmod) * T_DIM
                                  + r0 + 4 * lh) = v;
    }
}

extern "C" void kernel_launch(void* const* d_in, const int* in_sizes, int n_in,
                              void* d_out, int out_size, void* d_ws, size_t ws_size,
                              hipStream_t stream) {
    const float* u = (const float*)d_in[0];   // (1, 512, 128) fp32
    const float* s = (const float*)d_in[1];   // (65536, 512) fp32
    float* out = (float*)d_out;               // (128, 65536) fp32

    c2q_main<<<T_DIM / 128, 512, 0, stream>>>(s, u, out);
}